// Round 1
// baseline (253.609 us; speedup 1.0000x reference)
//
#include <hip/hip_runtime.h>

typedef _Float16 half8 __attribute__((ext_vector_type(8)));
typedef _Float16 half4_t __attribute__((ext_vector_type(4)));
typedef float f32x4 __attribute__((ext_vector_type(4)));

#define GK 1024

// ---------------- fp32 -> fp16 convert ----------------
__global__ void cvt_kernel(const float* __restrict__ src, _Float16* __restrict__ dst, int n) {
    int i = (blockIdx.x * 256 + threadIdx.x) * 4;
    if (i >= n) return;
    f32x4 v = *(const f32x4*)(src + i);
    half4_t h;
    h[0] = (_Float16)v[0]; h[1] = (_Float16)v[1];
    h[2] = (_Float16)v[2]; h[3] = (_Float16)v[3];
    *(half4_t*)(dst + i) = h;
}

// ---------------- GEMM: C[4096,1024] = A[4096,1024] @ B[1024,1024]^T ----------------
// MODE 0: z in {0,1,2} picks (B0,O0)/(B1,O1)/(B2,O2); epilogue scatters fp16 to [B,H,S,DK]
// MODE 1: epilogue writes fp32 row-major to Of
template<int MODE>
__global__ __launch_bounds__(256) void gemm_kernel(
    const _Float16* __restrict__ A,
    const _Float16* __restrict__ B0,
    const _Float16* __restrict__ B1,
    const _Float16* __restrict__ B2,
    _Float16* __restrict__ O0,
    _Float16* __restrict__ O1,
    _Float16* __restrict__ O2,
    float* __restrict__ Of)
{
    const _Float16* Bw = B0;
    _Float16* Oh = O0;
    if (MODE == 0) {
        int z = blockIdx.z;
        Bw = (z == 0) ? B0 : ((z == 1) ? B1 : B2);
        Oh = (z == 0) ? O0 : ((z == 1) ? O1 : O2);
    }
    __shared__ __attribute__((aligned(16))) _Float16 sA[128][32];
    __shared__ __attribute__((aligned(16))) _Float16 sB[128][32];

    const int tid = threadIdx.x;
    const int wave = tid >> 6, lane = tid & 63;
    const int quad = lane >> 4, l16 = lane & 15;
    const int wr = wave >> 1, wc = wave & 1;
    const int M0 = blockIdx.y * 128, N0 = blockIdx.x * 128;

    const int srow = tid >> 2;          // 0..63
    const int scol = (tid & 3) * 8;     // 0,8,16,24

    const half8* Ag0 = (const half8*)(A + (size_t)(M0 + srow) * GK + scol);
    const half8* Ag1 = (const half8*)(A + (size_t)(M0 + 64 + srow) * GK + scol);
    const half8* Bg0 = (const half8*)(Bw + (size_t)(N0 + srow) * GK + scol);
    const half8* Bg1 = (const half8*)(Bw + (size_t)(N0 + 64 + srow) * GK + scol);

    f32x4 acc[4][4] = {};
    half8 ra0 = Ag0[0], ra1 = Ag1[0], rb0 = Bg0[0], rb1 = Bg1[0];

    for (int kt = 0; kt < GK / 32; ++kt) {
        __syncthreads();
        *(half8*)&sA[srow][scol] = ra0;
        *(half8*)&sA[64 + srow][scol] = ra1;
        *(half8*)&sB[srow][scol] = rb0;
        *(half8*)&sB[64 + srow][scol] = rb1;
        __syncthreads();
        if (kt + 1 < GK / 32) {
            int off = (kt + 1) * 4;   // units of half8 (16B), 4 per BK=32
            ra0 = Ag0[off]; ra1 = Ag1[off]; rb0 = Bg0[off]; rb1 = Bg1[off];
        }
        half8 af[4], bf[4];
        #pragma unroll
        for (int i = 0; i < 4; ++i)
            af[i] = *(const half8*)&sA[wr * 64 + i * 16 + l16][quad * 8];
        #pragma unroll
        for (int j = 0; j < 4; ++j)
            bf[j] = *(const half8*)&sB[wc * 64 + j * 16 + l16][quad * 8];
        #pragma unroll
        for (int i = 0; i < 4; ++i)
            #pragma unroll
            for (int j = 0; j < 4; ++j)
                acc[i][j] = __builtin_amdgcn_mfma_f32_16x16x32_f16(af[i], bf[j], acc[i][j], 0, 0, 0);
    }

    #pragma unroll
    for (int i = 0; i < 4; ++i) {
        #pragma unroll
        for (int j = 0; j < 4; ++j) {
            #pragma unroll
            for (int r = 0; r < 4; ++r) {
                int m = M0 + wr * 64 + i * 16 + quad * 4 + r;
                int n = N0 + wc * 64 + j * 16 + l16;
                float v = acc[i][j][r];
                if (MODE == 0) {
                    int b = m >> 10, s = m & 1023, hh = n >> 6, d = n & 63;
                    Oh[((size_t)((b * 16 + hh) * 1024 + s)) * 64 + d] = (_Float16)v;
                } else {
                    Of[(size_t)m * 1024 + n] = v;
                }
            }
        }
    }
}

// ---------------- flash-style attention ----------------
// grid (16 qtiles, 16 heads, 4 batch), 256 threads; Q/K/V fp16 [B,H,S,64]
__global__ __launch_bounds__(256) void attn_kernel(
    const _Float16* __restrict__ Q,
    const _Float16* __restrict__ K,
    const _Float16* __restrict__ V,
    const float* __restrict__ rel_bias,   // [32][16]
    _Float16* __restrict__ ctx)           // [B*S, 1024]
{
    const int S = 1024;
    const int q0 = blockIdx.x * 64;
    const int h = blockIdx.y;
    const int b = blockIdx.z;
    const int bh = b * 16 + h;
    const _Float16* Qh = Q + (size_t)bh * S * 64;
    const _Float16* Kh = K + (size_t)bh * S * 64;
    const _Float16* Vh = V + (size_t)bh * S * 64;

    __shared__ __attribute__((aligned(16))) _Float16 sQ[64][64];
    __shared__ __attribute__((aligned(16))) _Float16 sK[64][64];
    __shared__ __attribute__((aligned(16))) _Float16 sVt[64][72];  // [d][kpos], padded
    __shared__ __attribute__((aligned(16))) _Float16 sP[4][16][64];
    __shared__ float sBias[1088];

    const int tid = threadIdx.x;
    const int wave = tid >> 6, lane = tid & 63;
    const int quad = lane >> 4, l16 = lane & 15;

    {   // stage Q tile (once)
        int r = tid >> 3, c = (tid & 7) * 8;
        *(half8*)&sQ[r][c]      = *(const half8*)(Qh + (size_t)(q0 + r) * 64 + c);
        *(half8*)&sQ[r + 32][c] = *(const half8*)(Qh + (size_t)(q0 + r + 32) * 64 + c);
    }
    // stage bias window: idx = kpos - q + q0 + 63 in [0,1086]
    for (int i = tid; i < 1087; i += 256) {
        int delta = i - (q0 + 63);             // kpos - q
        int rb = (delta > 0) ? 16 : 0;
        int n = (delta < 0) ? -delta : delta;
        int bucket;
        if (n < 8) bucket = rb + n;
        else bucket = rb + 8 + (n >= 12) + (n >= 16) + (n >= 23) + (n >= 32)
                             + (n >= 46) + (n >= 64) + (n >= 91);
        sBias[i] = rel_bias[bucket * 16 + h];
    }
    __syncthreads();

    half8 qf0 = *(const half8*)&sQ[wave * 16 + l16][quad * 8];
    half8 qf1 = *(const half8*)&sQ[wave * 16 + l16][32 + quad * 8];

    float m_run[4], l_run[4];
    f32x4 acc[4] = {};
    #pragma unroll
    for (int r = 0; r < 4; ++r) { m_run[r] = -INFINITY; l_run[r] = 0.0f; }

    for (int kt = 0; kt < 16; ++kt) {
        __syncthreads();   // protect sK/sVt/sP reuse
        {
            int r = tid >> 3, c = (tid & 7) * 8;
            *(half8*)&sK[r][c]      = *(const half8*)(Kh + (size_t)(kt * 64 + r) * 64 + c);
            *(half8*)&sK[r + 32][c] = *(const half8*)(Kh + (size_t)(kt * 64 + r + 32) * 64 + c);
            half8 v0 = *(const half8*)(Vh + (size_t)(kt * 64 + r) * 64 + c);
            half8 v1 = *(const half8*)(Vh + (size_t)(kt * 64 + r + 32) * 64 + c);
            #pragma unroll
            for (int ii = 0; ii < 8; ++ii) {
                sVt[c + ii][r]      = v0[ii];
                sVt[c + ii][r + 32] = v1[ii];
            }
        }
        __syncthreads();

        // scores: 16 q-rows x 64 kpos per wave
        f32x4 sc[4] = {};
        #pragma unroll
        for (int j = 0; j < 4; ++j) {
            half8 kf0 = *(const half8*)&sK[j * 16 + l16][quad * 8];
            half8 kf1 = *(const half8*)&sK[j * 16 + l16][32 + quad * 8];
            sc[j] = __builtin_amdgcn_mfma_f32_16x16x32_f16(qf0, kf0, sc[j], 0, 0, 0);
            sc[j] = __builtin_amdgcn_mfma_f32_16x16x32_f16(qf1, kf1, sc[j], 0, 0, 0);
        }

        // bias add: idx = kt*64 + j*16 + l16 - (wave*16 + quad*4 + r) + 63
        const int base_idx = kt * 64 + l16 - wave * 16 - quad * 4 + 63;
        #pragma unroll
        for (int j = 0; j < 4; ++j)
            #pragma unroll
            for (int r = 0; r < 4; ++r)
                sc[j][r] += sBias[base_idx + j * 16 - r];

        // online softmax per q-row (rows live on the 16 lanes of each quad-group)
        #pragma unroll
        for (int r = 0; r < 4; ++r) {
            float mx = fmaxf(fmaxf(sc[0][r], sc[1][r]), fmaxf(sc[2][r], sc[3][r]));
            mx = fmaxf(mx, __shfl_xor(mx, 1));
            mx = fmaxf(mx, __shfl_xor(mx, 2));
            mx = fmaxf(mx, __shfl_xor(mx, 4));
            mx = fmaxf(mx, __shfl_xor(mx, 8));
            float mnew = fmaxf(m_run[r], mx);
            float alpha = __expf(m_run[r] - mnew);
            m_run[r] = mnew;
            float psum = 0.0f;
            #pragma unroll
            for (int j = 0; j < 4; ++j) {
                float p = __expf(sc[j][r] - mnew);
                sc[j][r] = p;
                psum += p;
            }
            psum += __shfl_xor(psum, 1);
            psum += __shfl_xor(psum, 2);
            psum += __shfl_xor(psum, 4);
            psum += __shfl_xor(psum, 8);
            l_run[r] = l_run[r] * alpha + psum;
            #pragma unroll
            for (int dt = 0; dt < 4; ++dt) acc[dt][r] *= alpha;
        }

        // P (C-layout) -> LDS -> A-fragment layout
        #pragma unroll
        for (int j = 0; j < 4; ++j)
            #pragma unroll
            for (int r = 0; r < 4; ++r)
                sP[wave][quad * 4 + r][j * 16 + l16] = (_Float16)sc[j][r];
        __syncthreads();

        half8 pf0 = *(const half8*)&sP[wave][l16][quad * 8];
        half8 pf1 = *(const half8*)&sP[wave][l16][32 + quad * 8];
        #pragma unroll
        for (int dt = 0; dt < 4; ++dt) {
            half8 vf0 = *(const half8*)&sVt[dt * 16 + l16][quad * 8];
            half8 vf1 = *(const half8*)&sVt[dt * 16 + l16][32 + quad * 8];
            acc[dt] = __builtin_amdgcn_mfma_f32_16x16x32_f16(pf0, vf0, acc[dt], 0, 0, 0);
            acc[dt] = __builtin_amdgcn_mfma_f32_16x16x32_f16(pf1, vf1, acc[dt], 0, 0, 0);
        }
    }

    const int qrow = q0 + wave * 16 + quad * 4;
    #pragma unroll
    for (int r = 0; r < 4; ++r) {
        float inv = 1.0f / l_run[r];
        #pragma unroll
        for (int dt = 0; dt < 4; ++dt)
            ctx[((size_t)(b * 1024 + qrow + r)) * 1024 + h * 64 + dt * 16 + l16] =
                (_Float16)(acc[dt][r] * inv);
    }
}

// ---------------- launch ----------------
extern "C" void kernel_launch(void* const* d_in, const int* in_sizes, int n_in,
                              void* d_out, int out_size, void* d_ws, size_t ws_size,
                              hipStream_t stream) {
    const float* hidden   = (const float*)d_in[0];
    const float* Wq       = (const float*)d_in[1];
    const float* Wk       = (const float*)d_in[2];
    const float* Wv       = (const float*)d_in[3];
    const float* Wo       = (const float*)d_in[4];
    const float* rel_bias = (const float*)d_in[5];
    float* out = (float*)d_out;

    const size_t MEG = 1024 * 1024;
    _Float16* ws    = (_Float16*)d_ws;
    _Float16* h16   = ws;             // 4M halves
    _Float16* wq16  = ws + 4 * MEG;   // 1M
    _Float16* wk16  = ws + 5 * MEG;
    _Float16* wv16  = ws + 6 * MEG;
    _Float16* wo16  = ws + 7 * MEG;
    _Float16* Qs    = ws + 8 * MEG;   // [B,H,S,64] 4M
    _Float16* Ks    = ws + 12 * MEG;
    _Float16* Vs    = ws + 16 * MEG;
    _Float16* ctx16 = ws + 20 * MEG;  // [B*S,1024] 4M  (total 48 MB)

    cvt_kernel<<<4096, 256, 0, stream>>>(hidden, h16, 4 * MEG);
    cvt_kernel<<<1024, 256, 0, stream>>>(Wq, wq16, MEG);
    cvt_kernel<<<1024, 256, 0, stream>>>(Wk, wk16, MEG);
    cvt_kernel<<<1024, 256, 0, stream>>>(Wv, wv16, MEG);
    cvt_kernel<<<1024, 256, 0, stream>>>(Wo, wo16, MEG);

    gemm_kernel<0><<<dim3(8, 32, 3), 256, 0, stream>>>(
        h16, wq16, wk16, wv16, Qs, Ks, Vs, nullptr);

    attn_kernel<<<dim3(16, 16, 4), 256, 0, stream>>>(Qs, Ks, Vs, rel_bias, ctx16);

    gemm_kernel<1><<<dim3(8, 32, 1), 256, 0, stream>>>(
        ctx16, wo16, nullptr, nullptr, nullptr, nullptr, nullptr, out);
}

// Round 2
// 240.210 us; speedup vs baseline: 1.0558x; 1.0558x over previous
//
#include <hip/hip_runtime.h>

typedef _Float16 half8 __attribute__((ext_vector_type(8)));
typedef _Float16 half4_t __attribute__((ext_vector_type(4)));
typedef float f32x4 __attribute__((ext_vector_type(4)));

#define GK 1024
#define MEG (1024 * 1024)

// ---------------- fp32 -> fp16 convert (all 5 tensors, one launch) ----------------
__global__ void cvt_all_kernel(const float* __restrict__ hidden,
                               const float* __restrict__ Wq,
                               const float* __restrict__ Wk,
                               const float* __restrict__ Wv,
                               const float* __restrict__ Wo,
                               _Float16* __restrict__ ws) {
    int b = blockIdx.x;
    const float* src;
    _Float16* dst;
    if (b < 4096)      { src = hidden; dst = ws; }
    else if (b < 5120) { src = Wq; dst = ws + 4 * MEG; b -= 4096; }
    else if (b < 6144) { src = Wk; dst = ws + 5 * MEG; b -= 5120; }
    else if (b < 7168) { src = Wv; dst = ws + 6 * MEG; b -= 6144; }
    else               { src = Wo; dst = ws + 7 * MEG; b -= 7168; }
    int i = (b * 256 + threadIdx.x) * 4;
    f32x4 v = *(const f32x4*)(src + i);
    half4_t h;
    h[0] = (_Float16)v[0]; h[1] = (_Float16)v[1];
    h[2] = (_Float16)v[2]; h[3] = (_Float16)v[3];
    *(half4_t*)(dst + i) = h;
}

// ---------------- GEMM: C[4096,1024] = A[4096,1024] @ B[1024,1024]^T ----------------
// MODE 0: z in {0,1,2} picks (B0,O0)/(B1,O1)/(B2,O2); epilogue scatters fp16 to [B,H,S,DK]
// MODE 1: epilogue writes fp32 row-major to Of
template<int MODE>
__global__ __launch_bounds__(256) void gemm_kernel(
    const _Float16* __restrict__ A,
    const _Float16* __restrict__ B0,
    const _Float16* __restrict__ B1,
    const _Float16* __restrict__ B2,
    _Float16* __restrict__ O0,
    _Float16* __restrict__ O1,
    _Float16* __restrict__ O2,
    float* __restrict__ Of)
{
    const _Float16* Bw = B0;
    _Float16* Oh = O0;
    if (MODE == 0) {
        int z = blockIdx.z;
        Bw = (z == 0) ? B0 : ((z == 1) ? B1 : B2);
        Oh = (z == 0) ? O0 : ((z == 1) ? O1 : O2);
    }
    // pad 32 -> 40: row stride 80B = 20 dwords; 20*l16 mod 32 -> 2 lanes/bank (free)
    __shared__ __attribute__((aligned(16))) _Float16 sA[128][40];
    __shared__ __attribute__((aligned(16))) _Float16 sB[128][40];

    const int tid = threadIdx.x;
    const int wave = tid >> 6, lane = tid & 63;
    const int quad = lane >> 4, l16 = lane & 15;
    const int wr = wave >> 1, wc = wave & 1;
    const int M0 = blockIdx.y * 128, N0 = blockIdx.x * 128;

    const int srow = tid >> 2;          // 0..63
    const int scol = (tid & 3) * 8;     // 0,8,16,24

    const half8* Ag0 = (const half8*)(A + (size_t)(M0 + srow) * GK + scol);
    const half8* Ag1 = (const half8*)(A + (size_t)(M0 + 64 + srow) * GK + scol);
    const half8* Bg0 = (const half8*)(Bw + (size_t)(N0 + srow) * GK + scol);
    const half8* Bg1 = (const half8*)(Bw + (size_t)(N0 + 64 + srow) * GK + scol);

    f32x4 acc[4][4] = {};
    half8 ra0 = Ag0[0], ra1 = Ag1[0], rb0 = Bg0[0], rb1 = Bg1[0];

    for (int kt = 0; kt < GK / 32; ++kt) {
        __syncthreads();
        *(half8*)&sA[srow][scol] = ra0;
        *(half8*)&sA[64 + srow][scol] = ra1;
        *(half8*)&sB[srow][scol] = rb0;
        *(half8*)&sB[64 + srow][scol] = rb1;
        __syncthreads();
        if (kt + 1 < GK / 32) {
            int off = (kt + 1) * 4;   // units of half8 (16B), 4 per BK=32
            ra0 = Ag0[off]; ra1 = Ag1[off]; rb0 = Bg0[off]; rb1 = Bg1[off];
        }
        half8 af[4], bf[4];
        #pragma unroll
        for (int i = 0; i < 4; ++i)
            af[i] = *(const half8*)&sA[wr * 64 + i * 16 + l16][quad * 8];
        #pragma unroll
        for (int j = 0; j < 4; ++j)
            bf[j] = *(const half8*)&sB[wc * 64 + j * 16 + l16][quad * 8];
        #pragma unroll
        for (int i = 0; i < 4; ++i)
            #pragma unroll
            for (int j = 0; j < 4; ++j)
                acc[i][j] = __builtin_amdgcn_mfma_f32_16x16x32_f16(af[i], bf[j], acc[i][j], 0, 0, 0);
    }

    #pragma unroll
    for (int i = 0; i < 4; ++i) {
        #pragma unroll
        for (int j = 0; j < 4; ++j) {
            #pragma unroll
            for (int r = 0; r < 4; ++r) {
                int m = M0 + wr * 64 + i * 16 + quad * 4 + r;
                int n = N0 + wc * 64 + j * 16 + l16;
                float v = acc[i][j][r];
                if (MODE == 0) {
                    int b = m >> 10, s = m & 1023, hh = n >> 6, d = n & 63;
                    Oh[((size_t)((b * 16 + hh) * 1024 + s)) * 64 + d] = (_Float16)v;
                } else {
                    Of[(size_t)m * 1024 + n] = v;
                }
            }
        }
    }
}

// ---------------- V transpose: [BH][S][64] -> [BH][64][S] ----------------
// 64x64 LDS tile, pad 65 (stride 130B: lane-stride banks 2/bank on read -> free)
__global__ __launch_bounds__(256) void transpose_v_kernel(
    const _Float16* __restrict__ V, _Float16* __restrict__ VT) {
    __shared__ _Float16 tile[64][65];
    const int s0 = blockIdx.x * 64;
    const int bh = blockIdx.y;
    const _Float16* Vb = V + (size_t)bh * 1024 * 64;
    _Float16* Tb = VT + (size_t)bh * 64 * 1024;
    const int tr = threadIdx.x >> 6;   // 0..3
    const int tc = threadIdx.x & 63;
    #pragma unroll
    for (int i = 0; i < 16; ++i) {
        int r = i * 4 + tr;
        tile[r][tc] = Vb[(size_t)(s0 + r) * 64 + tc];   // coalesced 128B/wave
    }
    __syncthreads();
    #pragma unroll
    for (int i = 0; i < 16; ++i) {
        int d = i * 4 + tr;
        Tb[(size_t)d * 1024 + s0 + tc] = tile[tc][d];   // coalesced store
    }
}

// ---------------- flash-style attention ----------------
// grid (16 qtiles, 16 heads, 4 batch), 256 threads; Q/K fp16 [B,H,S,64], VT fp16 [B,H,64,S]
__global__ __launch_bounds__(256) void attn_kernel(
    const _Float16* __restrict__ Q,
    const _Float16* __restrict__ K,
    const _Float16* __restrict__ VT,
    const float* __restrict__ rel_bias,   // [32][16]
    _Float16* __restrict__ ctx)           // [B*S, 1024]
{
    const int S = 1024;
    const int q0 = blockIdx.x * 64;
    const int h = blockIdx.y;
    const int b = blockIdx.z;
    const int bh = b * 16 + h;
    const _Float16* Qh = Q + (size_t)bh * S * 64;
    const _Float16* Kh = K + (size_t)bh * S * 64;
    const _Float16* VTh = VT + (size_t)bh * 64 * S;

    // all inner dims padded to 72 (144B = 36 dwords): fragment reads 2 lanes/bank = free
    __shared__ __attribute__((aligned(16))) _Float16 sQ[64][72];
    __shared__ __attribute__((aligned(16))) _Float16 sK[64][72];
    __shared__ __attribute__((aligned(16))) _Float16 sVt[64][72];  // [d][kpos]
    __shared__ __attribute__((aligned(16))) _Float16 sP[4][16][72];
    __shared__ _Float16 sBias[1088];

    const int tid = threadIdx.x;
    const int wave = tid >> 6, lane = tid & 63;
    const int quad = lane >> 4, l16 = lane & 15;

    {   // stage Q tile (once)
        int r = tid >> 3, c = (tid & 7) * 8;
        *(half8*)&sQ[r][c]      = *(const half8*)(Qh + (size_t)(q0 + r) * 64 + c);
        *(half8*)&sQ[r + 32][c] = *(const half8*)(Qh + (size_t)(q0 + r + 32) * 64 + c);
    }
    // stage bias window: idx = kpos - q + q0 + 63 in [0,1086]
    for (int i = tid; i < 1087; i += 256) {
        int delta = i - (q0 + 63);             // kpos - q
        int rb = (delta > 0) ? 16 : 0;
        int n = (delta < 0) ? -delta : delta;
        int bucket;
        if (n < 8) bucket = rb + n;
        else bucket = rb + 8 + (n >= 12) + (n >= 16) + (n >= 23) + (n >= 32)
                             + (n >= 46) + (n >= 64) + (n >= 91);
        sBias[i] = (_Float16)rel_bias[bucket * 16 + h];
    }
    __syncthreads();

    half8 qf0 = *(const half8*)&sQ[wave * 16 + l16][quad * 8];
    half8 qf1 = *(const half8*)&sQ[wave * 16 + l16][32 + quad * 8];

    float m_run[4], l_run[4];
    f32x4 acc[4] = {};
    #pragma unroll
    for (int r = 0; r < 4; ++r) { m_run[r] = -INFINITY; l_run[r] = 0.0f; }

    for (int kt = 0; kt < 16; ++kt) {
        __syncthreads();   // protect sK/sVt reuse
        {
            int r = tid >> 3, c = (tid & 7) * 8;
            *(half8*)&sK[r][c]      = *(const half8*)(Kh + (size_t)(kt * 64 + r) * 64 + c);
            *(half8*)&sK[r + 32][c] = *(const half8*)(Kh + (size_t)(kt * 64 + r + 32) * 64 + c);
            // V^T rows: plain coalesced loads, no scatter
            *(half8*)&sVt[r][c]      = *(const half8*)(VTh + (size_t)r * S + kt * 64 + c);
            *(half8*)&sVt[r + 32][c] = *(const half8*)(VTh + (size_t)(r + 32) * S + kt * 64 + c);
        }
        __syncthreads();

        // scores: 16 q-rows x 64 kpos per wave
        f32x4 sc[4] = {};
        #pragma unroll
        for (int j = 0; j < 4; ++j) {
            half8 kf0 = *(const half8*)&sK[j * 16 + l16][quad * 8];
            half8 kf1 = *(const half8*)&sK[j * 16 + l16][32 + quad * 8];
            sc[j] = __builtin_amdgcn_mfma_f32_16x16x32_f16(qf0, kf0, sc[j], 0, 0, 0);
            sc[j] = __builtin_amdgcn_mfma_f32_16x16x32_f16(qf1, kf1, sc[j], 0, 0, 0);
        }

        // bias add: idx = kt*64 + j*16 + l16 - (wave*16 + quad*4 + r) + 63
        const int base_idx = kt * 64 + l16 - wave * 16 - quad * 4 + 63;
        #pragma unroll
        for (int j = 0; j < 4; ++j)
            #pragma unroll
            for (int r = 0; r < 4; ++r)
                sc[j][r] += (float)sBias[base_idx + j * 16 - r];

        // online softmax per q-row (rows live on the 16 lanes of each quad-group)
        #pragma unroll
        for (int r = 0; r < 4; ++r) {
            float mx = fmaxf(fmaxf(sc[0][r], sc[1][r]), fmaxf(sc[2][r], sc[3][r]));
            mx = fmaxf(mx, __shfl_xor(mx, 1));
            mx = fmaxf(mx, __shfl_xor(mx, 2));
            mx = fmaxf(mx, __shfl_xor(mx, 4));
            mx = fmaxf(mx, __shfl_xor(mx, 8));
            float mnew = fmaxf(m_run[r], mx);
            float alpha = __expf(m_run[r] - mnew);
            m_run[r] = mnew;
            float psum = 0.0f;
            #pragma unroll
            for (int j = 0; j < 4; ++j) {
                float p = __expf(sc[j][r] - mnew);
                sc[j][r] = p;
                psum += p;
            }
            psum += __shfl_xor(psum, 1);
            psum += __shfl_xor(psum, 2);
            psum += __shfl_xor(psum, 4);
            psum += __shfl_xor(psum, 8);
            l_run[r] = l_run[r] * alpha + psum;
            #pragma unroll
            for (int dt = 0; dt < 4; ++dt) acc[dt][r] *= alpha;
        }

        // P (C-layout) -> LDS -> A-fragment layout
        #pragma unroll
        for (int j = 0; j < 4; ++j)
            #pragma unroll
            for (int r = 0; r < 4; ++r)
                sP[wave][quad * 4 + r][j * 16 + l16] = (_Float16)sc[j][r];
        __syncthreads();

        half8 pf0 = *(const half8*)&sP[wave][l16][quad * 8];
        half8 pf1 = *(const half8*)&sP[wave][l16][32 + quad * 8];
        #pragma unroll
        for (int dt = 0; dt < 4; ++dt) {
            half8 vf0 = *(const half8*)&sVt[dt * 16 + l16][quad * 8];
            half8 vf1 = *(const half8*)&sVt[dt * 16 + l16][32 + quad * 8];
            acc[dt] = __builtin_amdgcn_mfma_f32_16x16x32_f16(pf0, vf0, acc[dt], 0, 0, 0);
            acc[dt] = __builtin_amdgcn_mfma_f32_16x16x32_f16(pf1, vf1, acc[dt], 0, 0, 0);
        }
    }

    const int qrow = q0 + wave * 16 + quad * 4;
    #pragma unroll
    for (int r = 0; r < 4; ++r) {
        float inv = 1.0f / l_run[r];
        #pragma unroll
        for (int dt = 0; dt < 4; ++dt)
            ctx[((size_t)(b * 1024 + qrow + r)) * 1024 + h * 64 + dt * 16 + l16] =
                (_Float16)(acc[dt][r] * inv);
    }
}

// ---------------- launch ----------------
extern "C" void kernel_launch(void* const* d_in, const int* in_sizes, int n_in,
                              void* d_out, int out_size, void* d_ws, size_t ws_size,
                              hipStream_t stream) {
    const float* hidden   = (const float*)d_in[0];
    const float* Wq       = (const float*)d_in[1];
    const float* Wk       = (const float*)d_in[2];
    const float* Wv       = (const float*)d_in[3];
    const float* Wo       = (const float*)d_in[4];
    const float* rel_bias = (const float*)d_in[5];
    float* out = (float*)d_out;

    _Float16* ws    = (_Float16*)d_ws;
    _Float16* h16   = ws;             // 4M halves (reused as VT after gemm<0>)
    _Float16* wq16  = ws + 4 * (size_t)MEG;   // 1M
    _Float16* wk16  = ws + 5 * (size_t)MEG;
    _Float16* wv16  = ws + 6 * (size_t)MEG;
    _Float16* wo16  = ws + 7 * (size_t)MEG;
    _Float16* Qs    = ws + 8 * (size_t)MEG;   // [B,H,S,64] 4M
    _Float16* Ks    = ws + 12 * (size_t)MEG;
    _Float16* Vs    = ws + 16 * (size_t)MEG;
    _Float16* ctx16 = ws + 20 * (size_t)MEG;  // [B*S,1024] 4M  (total 48 MB)
    _Float16* VTs   = h16;                    // V^T [B,H,64,S] — h16 is dead after gemm<0>

    cvt_all_kernel<<<8192, 256, 0, stream>>>(hidden, Wq, Wk, Wv, Wo, ws);

    gemm_kernel<0><<<dim3(8, 32, 3), 256, 0, stream>>>(
        h16, wq16, wk16, wv16, Qs, Ks, Vs, nullptr);

    transpose_v_kernel<<<dim3(16, 64), 256, 0, stream>>>(Vs, VTs);

    attn_kernel<<<dim3(16, 16, 4), 256, 0, stream>>>(Qs, Ks, VTs, rel_bias, ctx16);

    gemm_kernel<1><<<dim3(8, 32, 1), 256, 0, stream>>>(
        ctx16, wo16, nullptr, nullptr, nullptr, nullptr, nullptr, out);
}

// Round 7
// 239.615 us; speedup vs baseline: 1.0584x; 1.0025x over previous
//
#include <hip/hip_runtime.h>

typedef _Float16 half8 __attribute__((ext_vector_type(8)));
typedef _Float16 half4_t __attribute__((ext_vector_type(4)));
typedef float f32x4 __attribute__((ext_vector_type(4)));

#define GK 1024
#define MEG (1024 * 1024)

// async global->LDS, 16B per lane; lptr wave-uniform, lane i's data lands at lptr + i*16
#define GLD16(gptr, lptr) \
    __builtin_amdgcn_global_load_lds((const __attribute__((address_space(1))) void*)(gptr), \
                                     (__attribute__((address_space(3))) void*)(lptr), 16, 0, 0)

// ---------------- fp32 -> fp16 convert (all 5 tensors, one launch) ----------------
__global__ void cvt_all_kernel(const float* __restrict__ hidden,
                               const float* __restrict__ Wq,
                               const float* __restrict__ Wk,
                               const float* __restrict__ Wv,
                               const float* __restrict__ Wo,
                               _Float16* __restrict__ ws) {
    int b = blockIdx.x;
    const float* src;
    _Float16* dst;
    if (b < 4096)      { src = hidden; dst = ws; }
    else if (b < 5120) { src = Wq; dst = ws + 4 * MEG; b -= 4096; }
    else if (b < 6144) { src = Wk; dst = ws + 5 * MEG; b -= 5120; }
    else if (b < 7168) { src = Wv; dst = ws + 6 * MEG; b -= 6144; }
    else               { src = Wo; dst = ws + 7 * MEG; b -= 7168; }
    int i = (b * 256 + threadIdx.x) * 4;
    f32x4 v = *(const f32x4*)(src + i);
    half4_t h;
    h[0] = (_Float16)v[0]; h[1] = (_Float16)v[1];
    h[2] = (_Float16)v[2]; h[3] = (_Float16)v[3];
    *(half4_t*)(dst + i) = h;
}

// ---------------- GEMM: C[4096,1024] = A[4096,1024] @ B[1024,1024]^T ----------------
// m97-exact structure: global_load_lds width=16 into unpadded [128][32] LDS,
// straight lane mapping (lane -> row lane>>2, 16B chunk lane&3), 2 barriers/iter.
template<int MODE>
__global__ __launch_bounds__(256) void gemm_kernel(
    const _Float16* __restrict__ A,
    const _Float16* __restrict__ B0,
    const _Float16* __restrict__ B1,
    const _Float16* __restrict__ B2,
    _Float16* __restrict__ O0,
    _Float16* __restrict__ O1,
    _Float16* __restrict__ O2,
    float* __restrict__ Of)
{
    const _Float16* Bw = B0;
    _Float16* Oh = O0;
    if (MODE == 0) {
        int z = blockIdx.z;
        Bw = (z == 0) ? B0 : ((z == 1) ? B1 : B2);
        Oh = (z == 0) ? O0 : ((z == 1) ? O1 : O2);
    }
    __shared__ __attribute__((aligned(16))) _Float16 sA[128][32];
    __shared__ __attribute__((aligned(16))) _Float16 sB[128][32];

    const int tid = threadIdx.x;
    const int wave = tid >> 6, lane = tid & 63;
    const int quad = lane >> 4, l16 = lane & 15;
    const int wr = wave >> 1, wc = wave & 1;
    const int M0 = blockIdx.y * 128, N0 = blockIdx.x * 128;

    // staging source for this lane: row = wave*16 + (lane>>2), 16B chunk = lane&3
    const int rl = lane >> 2;
    const int cl = (lane & 3) * 8;   // halfs
    const size_t aOff0 = (size_t)(M0 + wave * 16 + rl) * GK + cl;
    const size_t aOff1 = aOff0 + (size_t)64 * GK;
    const size_t bOff0 = (size_t)(N0 + wave * 16 + rl) * GK + cl;
    const size_t bOff1 = bOff0 + (size_t)64 * GK;
    _Float16* ldsA0 = &sA[wave * 16][0];
    _Float16* ldsA1 = &sA[64 + wave * 16][0];
    _Float16* ldsB0 = &sB[wave * 16][0];
    _Float16* ldsB1 = &sB[64 + wave * 16][0];

    f32x4 acc[4][4] = {};

    for (int kt = 0; kt < GK / 32; ++kt) {
        const int ko = kt * 32;
        GLD16(A + aOff0 + ko, ldsA0);
        GLD16(A + aOff1 + ko, ldsA1);
        GLD16(Bw + bOff0 + ko, ldsB0);
        GLD16(Bw + bOff1 + ko, ldsB1);
        __syncthreads();                 // drains vmcnt(0): DMA landed for all waves
        half8 af[4], bf[4];
        #pragma unroll
        for (int i = 0; i < 4; ++i)
            af[i] = *(const half8*)&sA[wr * 64 + i * 16 + l16][quad * 8];
        #pragma unroll
        for (int j = 0; j < 4; ++j)
            bf[j] = *(const half8*)&sB[wc * 64 + j * 16 + l16][quad * 8];
        #pragma unroll
        for (int i = 0; i < 4; ++i)
            #pragma unroll
            for (int j = 0; j < 4; ++j)
                acc[i][j] = __builtin_amdgcn_mfma_f32_16x16x32_f16(af[i], bf[j], acc[i][j], 0, 0, 0);
        __syncthreads();                 // all reads done before next iter's DMA overwrites
    }

    #pragma unroll
    for (int i = 0; i < 4; ++i) {
        #pragma unroll
        for (int j = 0; j < 4; ++j) {
            #pragma unroll
            for (int r = 0; r < 4; ++r) {
                int m = M0 + wr * 64 + i * 16 + quad * 4 + r;
                int n = N0 + wc * 64 + j * 16 + l16;
                float v = acc[i][j][r];
                if (MODE == 0) {
                    int b = m >> 10, s = m & 1023, hh = n >> 6, d = n & 63;
                    Oh[((size_t)((b * 16 + hh) * 1024 + s)) * 64 + d] = (_Float16)v;
                } else {
                    Of[(size_t)m * 1024 + n] = v;
                }
            }
        }
    }
}

// ---------------- V transpose: [BH][S][64] -> [BH][64][S] (fp16) ----------------
__global__ __launch_bounds__(256) void transpose_v_kernel(
    const _Float16* __restrict__ V, _Float16* __restrict__ VT) {
    __shared__ _Float16 tile[64][65];
    const int s0 = blockIdx.x * 64;
    const int bh = blockIdx.y;
    const _Float16* Vb = V + (size_t)bh * 1024 * 64;
    _Float16* Tb = VT + (size_t)bh * 64 * 1024;
    const int tr = threadIdx.x >> 6;
    const int tc = threadIdx.x & 63;
    #pragma unroll
    for (int i = 0; i < 16; ++i) {
        int r = i * 4 + tr;
        tile[r][tc] = Vb[(size_t)(s0 + r) * 64 + tc];
    }
    __syncthreads();
    #pragma unroll
    for (int i = 0; i < 16; ++i) {
        int d = i * 4 + tr;
        Tb[(size_t)d * 1024 + s0 + tc] = tile[tc][d];
    }
}

// ---------------- flash-style attention (R2-exact: online max softmax) ----------------
// grid (16 qtiles, 16 heads, 4 batch), 256 threads; Q/K fp16 [B,H,S,64], VT fp16 [B,H,64,S]
__global__ __launch_bounds__(256) void attn_kernel(
    const _Float16* __restrict__ Q,
    const _Float16* __restrict__ K,
    const _Float16* __restrict__ VT,
    const float* __restrict__ rel_bias,   // [32][16]
    _Float16* __restrict__ ctx)           // [B*S, 1024]
{
    const int S = 1024;
    const int q0 = blockIdx.x * 64;
    const int h = blockIdx.y;
    const int b = blockIdx.z;
    const int bh = b * 16 + h;
    const _Float16* Qh = Q + (size_t)bh * S * 64;
    const _Float16* Kh = K + (size_t)bh * S * 64;
    const _Float16* VTh = VT + (size_t)bh * 64 * S;

    // inner dims padded to 72 (144B = 36 dwords): fragment reads 2 lanes/bank = free
    __shared__ __attribute__((aligned(16))) _Float16 sQ[64][72];
    __shared__ __attribute__((aligned(16))) _Float16 sK[64][72];
    __shared__ __attribute__((aligned(16))) _Float16 sVt[64][72];  // [d][kpos]
    __shared__ __attribute__((aligned(16))) _Float16 sP[4][16][72];
    __shared__ _Float16 sBias[1088];

    const int tid = threadIdx.x;
    const int wave = tid >> 6, lane = tid & 63;
    const int quad = lane >> 4, l16 = lane & 15;

    {   // stage Q tile (once)
        int r = tid >> 3, c = (tid & 7) * 8;
        *(half8*)&sQ[r][c]      = *(const half8*)(Qh + (size_t)(q0 + r) * 64 + c);
        *(half8*)&sQ[r + 32][c] = *(const half8*)(Qh + (size_t)(q0 + r + 32) * 64 + c);
    }
    // bias window: idx = kpos - q + q0 + 63 in [0,1086]
    for (int i = tid; i < 1087; i += 256) {
        int delta = i - (q0 + 63);             // kpos - q
        int rb = (delta > 0) ? 16 : 0;
        int n = (delta < 0) ? -delta : delta;
        int bucket;
        if (n < 8) bucket = rb + n;
        else bucket = rb + 8 + (n >= 12) + (n >= 16) + (n >= 23) + (n >= 32)
                             + (n >= 46) + (n >= 64) + (n >= 91);
        sBias[i] = (_Float16)rel_bias[bucket * 16 + h];
    }
    __syncthreads();

    half8 qf0 = *(const half8*)&sQ[wave * 16 + l16][quad * 8];
    half8 qf1 = *(const half8*)&sQ[wave * 16 + l16][32 + quad * 8];

    float m_run[4], l_run[4];
    f32x4 acc[4] = {};
    #pragma unroll
    for (int r = 0; r < 4; ++r) { m_run[r] = -INFINITY; l_run[r] = 0.0f; }

    for (int kt = 0; kt < 16; ++kt) {
        __syncthreads();   // protect sK/sVt reuse
        {
            int r = tid >> 3, c = (tid & 7) * 8;
            *(half8*)&sK[r][c]      = *(const half8*)(Kh + (size_t)(kt * 64 + r) * 64 + c);
            *(half8*)&sK[r + 32][c] = *(const half8*)(Kh + (size_t)(kt * 64 + r + 32) * 64 + c);
            *(half8*)&sVt[r][c]      = *(const half8*)(VTh + (size_t)r * S + kt * 64 + c);
            *(half8*)&sVt[r + 32][c] = *(const half8*)(VTh + (size_t)(r + 32) * S + kt * 64 + c);
        }
        __syncthreads();

        // scores: 16 q-rows x 64 kpos per wave
        f32x4 sc[4] = {};
        #pragma unroll
        for (int j = 0; j < 4; ++j) {
            half8 kf0 = *(const half8*)&sK[j * 16 + l16][quad * 8];
            half8 kf1 = *(const half8*)&sK[j * 16 + l16][32 + quad * 8];
            sc[j] = __builtin_amdgcn_mfma_f32_16x16x32_f16(qf0, kf0, sc[j], 0, 0, 0);
            sc[j] = __builtin_amdgcn_mfma_f32_16x16x32_f16(qf1, kf1, sc[j], 0, 0, 0);
        }

        // bias add: idx = kt*64 + j*16 + l16 - (wave*16 + quad*4 + r) + 63
        const int base_idx = kt * 64 + l16 - wave * 16 - quad * 4 + 63;
        #pragma unroll
        for (int j = 0; j < 4; ++j)
            #pragma unroll
            for (int r = 0; r < 4; ++r)
                sc[j][r] += (float)sBias[base_idx + j * 16 - r];

        // online softmax per q-row (rows live on the 16 lanes of each quad-group)
        #pragma unroll
        for (int r = 0; r < 4; ++r) {
            float mx = fmaxf(fmaxf(sc[0][r], sc[1][r]), fmaxf(sc[2][r], sc[3][r]));
            mx = fmaxf(mx, __shfl_xor(mx, 1));
            mx = fmaxf(mx, __shfl_xor(mx, 2));
            mx = fmaxf(mx, __shfl_xor(mx, 4));
            mx = fmaxf(mx, __shfl_xor(mx, 8));
            float mnew = fmaxf(m_run[r], mx);
            float alpha = __expf(m_run[r] - mnew);
            m_run[r] = mnew;
            float psum = 0.0f;
            #pragma unroll
            for (int j = 0; j < 4; ++j) {
                float p = __expf(sc[j][r] - mnew);
                sc[j][r] = p;
                psum += p;
            }
            psum += __shfl_xor(psum, 1);
            psum += __shfl_xor(psum, 2);
            psum += __shfl_xor(psum, 4);
            psum += __shfl_xor(psum, 8);
            l_run[r] = l_run[r] * alpha + psum;
            #pragma unroll
            for (int dt = 0; dt < 4; ++dt) acc[dt][r] *= alpha;
        }

        // P (C-layout) -> LDS -> A-fragment layout
        #pragma unroll
        for (int j = 0; j < 4; ++j)
            #pragma unroll
            for (int r = 0; r < 4; ++r)
                sP[wave][quad * 4 + r][j * 16 + l16] = (_Float16)sc[j][r];
        __syncthreads();

        half8 pf0 = *(const half8*)&sP[wave][l16][quad * 8];
        half8 pf1 = *(const half8*)&sP[wave][l16][32 + quad * 8];
        #pragma unroll
        for (int dt = 0; dt < 4; ++dt) {
            half8 vf0 = *(const half8*)&sVt[dt * 16 + l16][quad * 8];
            half8 vf1 = *(const half8*)&sVt[dt * 16 + l16][32 + quad * 8];
            acc[dt] = __builtin_amdgcn_mfma_f32_16x16x32_f16(pf0, vf0, acc[dt], 0, 0, 0);
            acc[dt] = __builtin_amdgcn_mfma_f32_16x16x32_f16(pf1, vf1, acc[dt], 0, 0, 0);
        }
    }

    const int qrow = q0 + wave * 16 + quad * 4;
    #pragma unroll
    for (int r = 0; r < 4; ++r) {
        float inv = 1.0f / l_run[r];
        #pragma unroll
        for (int dt = 0; dt < 4; ++dt)
            ctx[((size_t)(b * 1024 + qrow + r)) * 1024 + h * 64 + dt * 16 + l16] =
                (_Float16)(acc[dt][r] * inv);
    }
}

// ---------------- launch ----------------
extern "C" void kernel_launch(void* const* d_in, const int* in_sizes, int n_in,
                              void* d_out, int out_size, void* d_ws, size_t ws_size,
                              hipStream_t stream) {
    const float* hidden   = (const float*)d_in[0];
    const float* Wq       = (const float*)d_in[1];
    const float* Wk       = (const float*)d_in[2];
    const float* Wv       = (const float*)d_in[3];
    const float* Wo       = (const float*)d_in[4];
    const float* rel_bias = (const float*)d_in[5];
    float* out = (float*)d_out;

    _Float16* ws    = (_Float16*)d_ws;
    _Float16* h16   = ws;                     // 4M halves (reused as VT after gemm<0>)
    _Float16* wq16  = ws + 4 * (size_t)MEG;
    _Float16* wk16  = ws + 5 * (size_t)MEG;
    _Float16* wv16  = ws + 6 * (size_t)MEG;
    _Float16* wo16  = ws + 7 * (size_t)MEG;
    _Float16* Qs    = ws + 8 * (size_t)MEG;   // [B,H,S,64]
    _Float16* Ks    = ws + 12 * (size_t)MEG;
    _Float16* Vs    = ws + 16 * (size_t)MEG;
    _Float16* ctx16 = ws + 20 * (size_t)MEG;  // [B*S,1024]
    _Float16* VTs   = h16;                    // V^T [B,H,64,S] — h16 dead after gemm<0>

    cvt_all_kernel<<<8192, 256, 0, stream>>>(hidden, Wq, Wk, Wv, Wo, ws);

    gemm_kernel<0><<<dim3(8, 32, 3), 256, 0, stream>>>(
        h16, wq16, wk16, wv16, Qs, Ks, Vs, nullptr);

    transpose_v_kernel<<<dim3(16, 64), 256, 0, stream>>>(Vs, VTs);

    attn_kernel<<<dim3(16, 16, 4), 256, 0, stream>>>(Qs, Ks, VTs, rel_bias, ctx16);

    gemm_kernel<1><<<dim3(8, 32, 1), 256, 0, stream>>>(
        ctx16, wo16, nullptr, nullptr, nullptr, nullptr, nullptr, out);
}

// Round 8
// 217.879 us; speedup vs baseline: 1.1640x; 1.0998x over previous
//
#include <hip/hip_runtime.h>

typedef _Float16 half8 __attribute__((ext_vector_type(8)));
typedef _Float16 half4_t __attribute__((ext_vector_type(4)));
typedef float f32x4 __attribute__((ext_vector_type(4)));

#define GK 1024
#define MEG (1024 * 1024)

// async global->LDS, 16B per lane; lptr wave-uniform, lane i's data lands at lptr + i*16
#define GLD16(gptr, lptr) \
    __builtin_amdgcn_global_load_lds((const __attribute__((address_space(1))) void*)(gptr), \
                                     (__attribute__((address_space(3))) void*)(lptr), 16, 0, 0)

// ---------------- fp32 -> fp16 convert (all 5 tensors, one launch) ----------------
__global__ void cvt_all_kernel(const float* __restrict__ hidden,
                               const float* __restrict__ Wq,
                               const float* __restrict__ Wk,
                               const float* __restrict__ Wv,
                               const float* __restrict__ Wo,
                               _Float16* __restrict__ ws) {
    int b = blockIdx.x;
    const float* src;
    _Float16* dst;
    if (b < 4096)      { src = hidden; dst = ws; }
    else if (b < 5120) { src = Wq; dst = ws + 4 * MEG; b -= 4096; }
    else if (b < 6144) { src = Wk; dst = ws + 5 * MEG; b -= 5120; }
    else if (b < 7168) { src = Wv; dst = ws + 6 * MEG; b -= 6144; }
    else               { src = Wo; dst = ws + 7 * MEG; b -= 7168; }
    int i = (b * 256 + threadIdx.x) * 4;
    f32x4 v = *(const f32x4*)(src + i);
    half4_t h;
    h[0] = (_Float16)v[0]; h[1] = (_Float16)v[1];
    h[2] = (_Float16)v[2]; h[3] = (_Float16)v[3];
    *(half4_t*)(dst + i) = h;
}

// ---------------- GEMM: C[4096,1024] = A[4096,1024] @ B[1024,1024]^T ----------------
// R7-proven: global_load_lds width=16 into unpadded [128][32] LDS, straight lane map.
template<int MODE>
__global__ __launch_bounds__(256) void gemm_kernel(
    const _Float16* __restrict__ A,
    const _Float16* __restrict__ B0,
    const _Float16* __restrict__ B1,
    const _Float16* __restrict__ B2,
    _Float16* __restrict__ O0,
    _Float16* __restrict__ O1,
    _Float16* __restrict__ O2,
    float* __restrict__ Of)
{
    const _Float16* Bw = B0;
    _Float16* Oh = O0;
    if (MODE == 0) {
        int z = blockIdx.z;
        Bw = (z == 0) ? B0 : ((z == 1) ? B1 : B2);
        Oh = (z == 0) ? O0 : ((z == 1) ? O1 : O2);
    }
    __shared__ __attribute__((aligned(16))) _Float16 sA[128][32];
    __shared__ __attribute__((aligned(16))) _Float16 sB[128][32];

    const int tid = threadIdx.x;
    const int wave = tid >> 6, lane = tid & 63;
    const int quad = lane >> 4, l16 = lane & 15;
    const int wr = wave >> 1, wc = wave & 1;
    const int M0 = blockIdx.y * 128, N0 = blockIdx.x * 128;

    const int rl = lane >> 2;
    const int cl = (lane & 3) * 8;   // halfs
    const size_t aOff0 = (size_t)(M0 + wave * 16 + rl) * GK + cl;
    const size_t aOff1 = aOff0 + (size_t)64 * GK;
    const size_t bOff0 = (size_t)(N0 + wave * 16 + rl) * GK + cl;
    const size_t bOff1 = bOff0 + (size_t)64 * GK;
    _Float16* ldsA0 = &sA[wave * 16][0];
    _Float16* ldsA1 = &sA[64 + wave * 16][0];
    _Float16* ldsB0 = &sB[wave * 16][0];
    _Float16* ldsB1 = &sB[64 + wave * 16][0];

    f32x4 acc[4][4] = {};

    for (int kt = 0; kt < GK / 32; ++kt) {
        const int ko = kt * 32;
        GLD16(A + aOff0 + ko, ldsA0);
        GLD16(A + aOff1 + ko, ldsA1);
        GLD16(Bw + bOff0 + ko, ldsB0);
        GLD16(Bw + bOff1 + ko, ldsB1);
        __syncthreads();                 // drains vmcnt(0): DMA landed for all waves
        half8 af[4], bf[4];
        #pragma unroll
        for (int i = 0; i < 4; ++i)
            af[i] = *(const half8*)&sA[wr * 64 + i * 16 + l16][quad * 8];
        #pragma unroll
        for (int j = 0; j < 4; ++j)
            bf[j] = *(const half8*)&sB[wc * 64 + j * 16 + l16][quad * 8];
        #pragma unroll
        for (int i = 0; i < 4; ++i)
            #pragma unroll
            for (int j = 0; j < 4; ++j)
                acc[i][j] = __builtin_amdgcn_mfma_f32_16x16x32_f16(af[i], bf[j], acc[i][j], 0, 0, 0);
        __syncthreads();                 // all reads done before next iter's DMA overwrites
    }

    #pragma unroll
    for (int i = 0; i < 4; ++i) {
        #pragma unroll
        for (int j = 0; j < 4; ++j) {
            #pragma unroll
            for (int r = 0; r < 4; ++r) {
                int m = M0 + wr * 64 + i * 16 + quad * 4 + r;
                int n = N0 + wc * 64 + j * 16 + l16;
                float v = acc[i][j][r];
                if (MODE == 0) {
                    int b = m >> 10, s = m & 1023, hh = n >> 6, d = n & 63;
                    Oh[((size_t)((b * 16 + hh) * 1024 + s)) * 64 + d] = (_Float16)v;
                } else {
                    Of[(size_t)m * 1024 + n] = v;
                }
            }
        }
    }
}

// ---------------- V transpose: [BH][S][64] -> [BH][64][S] (fp16) ----------------
__global__ __launch_bounds__(256) void transpose_v_kernel(
    const _Float16* __restrict__ V, _Float16* __restrict__ VT) {
    __shared__ _Float16 tile[64][65];
    const int s0 = blockIdx.x * 64;
    const int bh = blockIdx.y;
    const _Float16* Vb = V + (size_t)bh * 1024 * 64;
    _Float16* Tb = VT + (size_t)bh * 64 * 1024;
    const int tr = threadIdx.x >> 6;
    const int tc = threadIdx.x & 63;
    #pragma unroll
    for (int i = 0; i < 16; ++i) {
        int r = i * 4 + tr;
        tile[r][tc] = Vb[(size_t)(s0 + r) * 64 + tc];
    }
    __syncthreads();
    #pragma unroll
    for (int i = 0; i < 16; ++i) {
        int d = i * 4 + tr;
        Tb[(size_t)d * 1024 + s0 + tc] = tile[tc][d];
    }
}

// ---------------- flash attention, TRANSPOSED scores (K·Q^T) ----------------
// Each lane owns ONE q-row (q = l16 within wave group): softmax reduce = 2 shfls.
// Layout facts reused from R7 (proven): mfma(X,Y) -> D[m][n] = sum_k X[m,k]*Y[n,k],
// both operands lane-mapped [row=l16][k=quad*8+jj]; C/D: row=quad*4+r, col=l16.
__global__ __launch_bounds__(256) void attn_kernel(
    const _Float16* __restrict__ Q,
    const _Float16* __restrict__ K,
    const _Float16* __restrict__ VT,
    const float* __restrict__ rel_bias,   // [32][16]
    _Float16* __restrict__ ctx)           // [B*S, 1024]
{
    const int S = 1024;
    const int q0 = blockIdx.x * 64;
    const int h = blockIdx.y;
    const int b = blockIdx.z;
    const int bh = b * 16 + h;
    const _Float16* Qh = Q + (size_t)bh * S * 64;
    const _Float16* Kh = K + (size_t)bh * S * 64;
    const _Float16* VTh = VT + (size_t)bh * 64 * S;

    __shared__ __attribute__((aligned(16))) _Float16 sQ[64][72];
    __shared__ __attribute__((aligned(16))) _Float16 sK[64][72];
    __shared__ __attribute__((aligned(16))) _Float16 sVt[64][72];   // [d][kpos]
    __shared__ __attribute__((aligned(16))) _Float16 sP[4][16][72]; // [wave][q=l16][kpos]
    __shared__ _Float16 sBias[1088];

    const int tid = threadIdx.x;
    const int wave = tid >> 6, lane = tid & 63;
    const int quad = lane >> 4, l16 = lane & 15;

    {   // stage Q tile (once)
        int r = tid >> 3, c = (tid & 7) * 8;
        *(half8*)&sQ[r][c]      = *(const half8*)(Qh + (size_t)(q0 + r) * 64 + c);
        *(half8*)&sQ[r + 32][c] = *(const half8*)(Qh + (size_t)(q0 + r + 32) * 64 + c);
    }
    // bias window: idx = kpos - q + q0 + 63 in [0,1086]
    for (int i = tid; i < 1087; i += 256) {
        int delta = i - (q0 + 63);             // kpos - q
        int rb = (delta > 0) ? 16 : 0;
        int n = (delta < 0) ? -delta : delta;
        int bucket;
        if (n < 8) bucket = rb + n;
        else bucket = rb + 8 + (n >= 12) + (n >= 16) + (n >= 23) + (n >= 32)
                             + (n >= 46) + (n >= 64) + (n >= 91);
        sBias[i] = (_Float16)rel_bias[bucket * 16 + h];
    }
    __syncthreads();

    // q-fragment: this wave's 16 q-rows (B-operand; lane l16 = q within group)
    half8 qf0 = *(const half8*)&sQ[wave * 16 + l16][quad * 8];
    half8 qf1 = *(const half8*)&sQ[wave * 16 + l16][32 + quad * 8];

    float m_run = -INFINITY, l_run = 0.0f;
    f32x4 acc[4] = {};   // acc[dt][r] = out^T[d = dt*16+quad*4+r][q = l16]

    for (int kt = 0; kt < 16; ++kt) {
        __syncthreads();   // prior iter's sK/sVt/sP reads done
        {
            int r = tid >> 3, c = (tid & 7) * 8;
            *(half8*)&sK[r][c]      = *(const half8*)(Kh + (size_t)(kt * 64 + r) * 64 + c);
            *(half8*)&sK[r + 32][c] = *(const half8*)(Kh + (size_t)(kt * 64 + r + 32) * 64 + c);
            *(half8*)&sVt[r][c]      = *(const half8*)(VTh + (size_t)r * S + kt * 64 + c);
            *(half8*)&sVt[r + 32][c] = *(const half8*)(VTh + (size_t)(r + 32) * S + kt * 64 + c);
        }
        __syncthreads();

        // scores transposed: sc[j][r] = S[kpos = kt*64 + j*16 + quad*4 + r][q = l16]
        f32x4 sc[4] = {};
        #pragma unroll
        for (int j = 0; j < 4; ++j) {
            half8 kf0 = *(const half8*)&sK[j * 16 + l16][quad * 8];
            half8 kf1 = *(const half8*)&sK[j * 16 + l16][32 + quad * 8];
            sc[j] = __builtin_amdgcn_mfma_f32_16x16x32_f16(kf0, qf0, sc[j], 0, 0, 0);
            sc[j] = __builtin_amdgcn_mfma_f32_16x16x32_f16(kf1, qf1, sc[j], 0, 0, 0);
        }

        // bias: idx = kpos - q + q0 + 63
        const int bbase = kt * 64 + quad * 4 - wave * 16 - l16 + 63;
        #pragma unroll
        for (int j = 0; j < 4; ++j)
            #pragma unroll
            for (int r = 0; r < 4; ++r)
                sc[j][r] += (float)sBias[bbase + j * 16 + r];

        // online softmax: each lane owns one q-row's 16 kpos values
        float mx = fmaxf(fmaxf(fmaxf(sc[0][0], sc[0][1]), fmaxf(sc[0][2], sc[0][3])),
                         fmaxf(fmaxf(sc[1][0], sc[1][1]), fmaxf(sc[1][2], sc[1][3])));
        mx = fmaxf(mx, fmaxf(fmaxf(fmaxf(sc[2][0], sc[2][1]), fmaxf(sc[2][2], sc[2][3])),
                             fmaxf(fmaxf(sc[3][0], sc[3][1]), fmaxf(sc[3][2], sc[3][3]))));
        mx = fmaxf(mx, __shfl_xor(mx, 16));
        mx = fmaxf(mx, __shfl_xor(mx, 32));
        float mnew = fmaxf(m_run, mx);
        float alpha = __expf(m_run - mnew);
        m_run = mnew;

        float ps = 0.0f;
        #pragma unroll
        for (int j = 0; j < 4; ++j) {
            half4_t pw;
            #pragma unroll
            for (int r = 0; r < 4; ++r) {
                float p = __expf(sc[j][r] - mnew);
                ps += p;
                pw[r] = (_Float16)p;
            }
            *(half4_t*)&sP[wave][l16][j * 16 + quad * 4] = pw;  // P[q=l16][kpos], b64 write
        }
        l_run = l_run * alpha + ps;
        #pragma unroll
        for (int dt = 0; dt < 4; ++dt) acc[dt] *= alpha;
        __syncthreads();   // sP write -> read ordering (R7-proven structure)

        half8 pf0 = *(const half8*)&sP[wave][l16][quad * 8];        // B[n=q][k=kpos 0..31]
        half8 pf1 = *(const half8*)&sP[wave][l16][32 + quad * 8];   // kpos 32..63
        #pragma unroll
        for (int dt = 0; dt < 4; ++dt) {
            half8 vf0 = *(const half8*)&sVt[dt * 16 + l16][quad * 8];      // A[m=d][k=kpos]
            half8 vf1 = *(const half8*)&sVt[dt * 16 + l16][32 + quad * 8];
            acc[dt] = __builtin_amdgcn_mfma_f32_16x16x32_f16(vf0, pf0, acc[dt], 0, 0, 0);
            acc[dt] = __builtin_amdgcn_mfma_f32_16x16x32_f16(vf1, pf1, acc[dt], 0, 0, 0);
        }
    }

    // final: reduce row-sum across quads, normalize, store half4 chunks
    l_run += __shfl_xor(l_run, 16);
    l_run += __shfl_xor(l_run, 32);
    const float inv = 1.0f / l_run;
    const size_t qg = (size_t)(b * 1024 + q0 + wave * 16 + l16);
    #pragma unroll
    for (int dt = 0; dt < 4; ++dt) {
        half4_t o;
        #pragma unroll
        for (int r = 0; r < 4; ++r) o[r] = (_Float16)(acc[dt][r] * inv);
        *(half4_t*)&ctx[qg * 1024 + h * 64 + dt * 16 + quad * 4] = o;
    }
}

// ---------------- launch ----------------
extern "C" void kernel_launch(void* const* d_in, const int* in_sizes, int n_in,
                              void* d_out, int out_size, void* d_ws, size_t ws_size,
                              hipStream_t stream) {
    const float* hidden   = (const float*)d_in[0];
    const float* Wq       = (const float*)d_in[1];
    const float* Wk       = (const float*)d_in[2];
    const float* Wv       = (const float*)d_in[3];
    const float* Wo       = (const float*)d_in[4];
    const float* rel_bias = (const float*)d_in[5];
    float* out = (float*)d_out;

    _Float16* ws    = (_Float16*)d_ws;
    _Float16* h16   = ws;                     // 4M halves (reused as VT after gemm<0>)
    _Float16* wq16  = ws + 4 * (size_t)MEG;
    _Float16* wk16  = ws + 5 * (size_t)MEG;
    _Float16* wv16  = ws + 6 * (size_t)MEG;
    _Float16* wo16  = ws + 7 * (size_t)MEG;
    _Float16* Qs    = ws + 8 * (size_t)MEG;   // [B,H,S,64]
    _Float16* Ks    = ws + 12 * (size_t)MEG;
    _Float16* Vs    = ws + 16 * (size_t)MEG;
    _Float16* ctx16 = ws + 20 * (size_t)MEG;  // [B*S,1024]
    _Float16* VTs   = h16;                    // V^T [B,H,64,S] — h16 dead after gemm<0>

    cvt_all_kernel<<<8192, 256, 0, stream>>>(hidden, Wq, Wk, Wv, Wo, ws);

    gemm_kernel<0><<<dim3(8, 32, 3), 256, 0, stream>>>(
        h16, wq16, wk16, wv16, Qs, Ks, Vs, nullptr);

    transpose_v_kernel<<<dim3(16, 64), 256, 0, stream>>>(Vs, VTs);

    attn_kernel<<<dim3(16, 16, 4), 256, 0, stream>>>(Qs, Ks, VTs, rel_bias, ctx16);

    gemm_kernel<1><<<dim3(8, 32, 1), 256, 0, stream>>>(
        ctx16, wo16, nullptr, nullptr, nullptr, nullptr, nullptr, out);
}

// Round 9
// 206.744 us; speedup vs baseline: 1.2267x; 1.0539x over previous
//
#include <hip/hip_runtime.h>

typedef _Float16 half8 __attribute__((ext_vector_type(8)));
typedef _Float16 half4_t __attribute__((ext_vector_type(4)));
typedef float f32x4 __attribute__((ext_vector_type(4)));

#define GK 1024
#define MEG (1024 * 1024)

// async global->LDS, 16B per lane; lptr wave-uniform, lane i's data lands at lptr + i*16
#define GLD16(gptr, lptr) \
    __builtin_amdgcn_global_load_lds((const __attribute__((address_space(1))) void*)(gptr), \
                                     (__attribute__((address_space(3))) void*)(lptr), 16, 0, 0)

// ---------------- fp32 -> fp16 convert (all 5 tensors, one launch) ----------------
__global__ void cvt_all_kernel(const float* __restrict__ hidden,
                               const float* __restrict__ Wq,
                               const float* __restrict__ Wk,
                               const float* __restrict__ Wv,
                               const float* __restrict__ Wo,
                               _Float16* __restrict__ ws) {
    int b = blockIdx.x;
    const float* src;
    _Float16* dst;
    if (b < 4096)      { src = hidden; dst = ws; }
    else if (b < 5120) { src = Wq; dst = ws + 4 * MEG; b -= 4096; }
    else if (b < 6144) { src = Wk; dst = ws + 5 * MEG; b -= 5120; }
    else if (b < 7168) { src = Wv; dst = ws + 6 * MEG; b -= 6144; }
    else               { src = Wo; dst = ws + 7 * MEG; b -= 7168; }
    int i = (b * 256 + threadIdx.x) * 4;
    f32x4 v = *(const f32x4*)(src + i);
    half4_t h;
    h[0] = (_Float16)v[0]; h[1] = (_Float16)v[1];
    h[2] = (_Float16)v[2]; h[3] = (_Float16)v[3];
    *(half4_t*)(dst + i) = h;
}

// ---------------- GEMM: C[4096,1024] = A[4096,1024] @ B[1024,1024]^T ----------------
// R7-proven GLD16 mechanics, BK=64 via two 32-col chunk buffers: halves barrier drains.
template<int MODE>
__global__ __launch_bounds__(256) void gemm_kernel(
    const _Float16* __restrict__ A,
    const _Float16* __restrict__ B0,
    const _Float16* __restrict__ B1,
    const _Float16* __restrict__ B2,
    _Float16* __restrict__ O0,
    _Float16* __restrict__ O1,
    _Float16* __restrict__ O2,
    float* __restrict__ Of)
{
    const _Float16* Bw = B0;
    _Float16* Oh = O0;
    if (MODE == 0) {
        int z = blockIdx.z;
        Bw = (z == 0) ? B0 : ((z == 1) ? B1 : B2);
        Oh = (z == 0) ? O0 : ((z == 1) ? O1 : O2);
    }
    // two k-chunks of 32 halfs each (R7-proven [128][32] layout per chunk)
    __shared__ __attribute__((aligned(16))) _Float16 sA[2][128][32];
    __shared__ __attribute__((aligned(16))) _Float16 sB[2][128][32];

    const int tid = threadIdx.x;
    const int wave = tid >> 6, lane = tid & 63;
    const int quad = lane >> 4, l16 = lane & 15;
    const int wr = wave >> 1, wc = wave & 1;
    const int M0 = blockIdx.y * 128, N0 = blockIdx.x * 128;

    // staging: per GLD16, lane -> row lane>>2 (16 rows), 16B chunk lane&3 within 32 halfs
    const int rl = lane >> 2;
    const int cl = (lane & 3) * 8;   // halfs within chunk
    const size_t aRow0 = (size_t)(M0 + wave * 16 + rl) * GK + cl;
    const size_t aRow1 = aRow0 + (size_t)64 * GK;
    const size_t bRow0 = (size_t)(N0 + wave * 16 + rl) * GK + cl;
    const size_t bRow1 = bRow0 + (size_t)64 * GK;
    _Float16* ldsA[2][2] = {{&sA[0][wave * 16][0], &sA[0][64 + wave * 16][0]},
                            {&sA[1][wave * 16][0], &sA[1][64 + wave * 16][0]}};
    _Float16* ldsB[2][2] = {{&sB[0][wave * 16][0], &sB[0][64 + wave * 16][0]},
                            {&sB[1][wave * 16][0], &sB[1][64 + wave * 16][0]}};

    f32x4 acc[4][4] = {};

    for (int kt = 0; kt < GK / 64; ++kt) {
        const int ko = kt * 64;
        #pragma unroll
        for (int c = 0; c < 2; ++c) {
            GLD16(A + aRow0 + ko + c * 32, ldsA[c][0]);
            GLD16(A + aRow1 + ko + c * 32, ldsA[c][1]);
            GLD16(Bw + bRow0 + ko + c * 32, ldsB[c][0]);
            GLD16(Bw + bRow1 + ko + c * 32, ldsB[c][1]);
        }
        __syncthreads();                 // drains vmcnt(0): both chunks landed
        #pragma unroll
        for (int c = 0; c < 2; ++c) {
            half8 af[4], bf[4];
            #pragma unroll
            for (int i = 0; i < 4; ++i)
                af[i] = *(const half8*)&sA[c][wr * 64 + i * 16 + l16][quad * 8];
            #pragma unroll
            for (int j = 0; j < 4; ++j)
                bf[j] = *(const half8*)&sB[c][wc * 64 + j * 16 + l16][quad * 8];
            #pragma unroll
            for (int i = 0; i < 4; ++i)
                #pragma unroll
                for (int j = 0; j < 4; ++j)
                    acc[i][j] = __builtin_amdgcn_mfma_f32_16x16x32_f16(af[i], bf[j], acc[i][j], 0, 0, 0);
        }
        __syncthreads();                 // all reads done before next iter's DMA overwrites
    }

    #pragma unroll
    for (int i = 0; i < 4; ++i) {
        #pragma unroll
        for (int j = 0; j < 4; ++j) {
            #pragma unroll
            for (int r = 0; r < 4; ++r) {
                int m = M0 + wr * 64 + i * 16 + quad * 4 + r;
                int n = N0 + wc * 64 + j * 16 + l16;
                float v = acc[i][j][r];
                if (MODE == 0) {
                    int b = m >> 10, s = m & 1023, hh = n >> 6, d = n & 63;
                    Oh[((size_t)((b * 16 + hh) * 1024 + s)) * 64 + d] = (_Float16)v;
                } else {
                    Of[(size_t)m * 1024 + n] = v;
                }
            }
        }
    }
}

// ---------------- V transpose: [BH][S][64] -> [BH][64][S] (fp16) ----------------
__global__ __launch_bounds__(256) void transpose_v_kernel(
    const _Float16* __restrict__ V, _Float16* __restrict__ VT) {
    __shared__ _Float16 tile[64][65];
    const int s0 = blockIdx.x * 64;
    const int bh = blockIdx.y;
    const _Float16* Vb = V + (size_t)bh * 1024 * 64;
    _Float16* Tb = VT + (size_t)bh * 64 * 1024;
    const int tr = threadIdx.x >> 6;
    const int tc = threadIdx.x & 63;
    #pragma unroll
    for (int i = 0; i < 16; ++i) {
        int r = i * 4 + tr;
        tile[r][tc] = Vb[(size_t)(s0 + r) * 64 + tc];
    }
    __syncthreads();
    #pragma unroll
    for (int i = 0; i < 16; ++i) {
        int d = i * 4 + tr;
        Tb[(size_t)d * 1024 + s0 + tc] = tile[tc][d];
    }
}

// ---------------- flash attention, TRANSPOSED scores (K·Q^T) ----------------
// R8-proven structure. New: uniform-distance tiles (|kt-qt|>=3 -> every delta >=129,
// same bucket across the tile) take ONE sBias read instead of 16 (same array, same math).
__global__ __launch_bounds__(256) void attn_kernel(
    const _Float16* __restrict__ Q,
    const _Float16* __restrict__ K,
    const _Float16* __restrict__ VT,
    const float* __restrict__ rel_bias,   // [32][16]
    _Float16* __restrict__ ctx)           // [B*S, 1024]
{
    const int S = 1024;
    const int qt = blockIdx.x;
    const int q0 = qt * 64;
    const int h = blockIdx.y;
    const int b = blockIdx.z;
    const int bh = b * 16 + h;
    const _Float16* Qh = Q + (size_t)bh * S * 64;
    const _Float16* Kh = K + (size_t)bh * S * 64;
    const _Float16* VTh = VT + (size_t)bh * 64 * S;

    __shared__ __attribute__((aligned(16))) _Float16 sQ[64][72];
    __shared__ __attribute__((aligned(16))) _Float16 sK[64][72];
    __shared__ __attribute__((aligned(16))) _Float16 sVt[64][72];   // [d][kpos]
    __shared__ __attribute__((aligned(16))) _Float16 sP[4][16][72]; // [wave][q=l16][kpos]
    __shared__ _Float16 sBias[1088];

    const int tid = threadIdx.x;
    const int wave = tid >> 6, lane = tid & 63;
    const int quad = lane >> 4, l16 = lane & 15;

    {   // stage Q tile (once)
        int r = tid >> 3, c = (tid & 7) * 8;
        *(half8*)&sQ[r][c]      = *(const half8*)(Qh + (size_t)(q0 + r) * 64 + c);
        *(half8*)&sQ[r + 32][c] = *(const half8*)(Qh + (size_t)(q0 + r + 32) * 64 + c);
    }
    // bias window: idx = kpos - q + q0 + 63 in [0,1086]
    for (int i = tid; i < 1087; i += 256) {
        int delta = i - (q0 + 63);             // kpos - q
        int rb = (delta > 0) ? 16 : 0;
        int n = (delta < 0) ? -delta : delta;
        int bucket;
        if (n < 8) bucket = rb + n;
        else bucket = rb + 8 + (n >= 12) + (n >= 16) + (n >= 23) + (n >= 32)
                             + (n >= 46) + (n >= 64) + (n >= 91);
        sBias[i] = (_Float16)rel_bias[bucket * 16 + h];
    }
    __syncthreads();

    // q-fragment: this wave's 16 q-rows (B-operand; lane l16 = q within group)
    half8 qf0 = *(const half8*)&sQ[wave * 16 + l16][quad * 8];
    half8 qf1 = *(const half8*)&sQ[wave * 16 + l16][32 + quad * 8];

    float m_run = -INFINITY, l_run = 0.0f;
    f32x4 acc[4] = {};   // acc[dt][r] = out^T[d = dt*16+quad*4+r][q = l16]

    for (int kt = 0; kt < 16; ++kt) {
        __syncthreads();   // prior iter's sK/sVt/sP reads done
        {
            int r = tid >> 3, c = (tid & 7) * 8;
            *(half8*)&sK[r][c]      = *(const half8*)(Kh + (size_t)(kt * 64 + r) * 64 + c);
            *(half8*)&sK[r + 32][c] = *(const half8*)(Kh + (size_t)(kt * 64 + r + 32) * 64 + c);
            *(half8*)&sVt[r][c]      = *(const half8*)(VTh + (size_t)r * S + kt * 64 + c);
            *(half8*)&sVt[r + 32][c] = *(const half8*)(VTh + (size_t)(r + 32) * S + kt * 64 + c);
        }
        __syncthreads();

        // scores transposed: sc[j][r] = S[kpos = kt*64 + j*16 + quad*4 + r][q = l16]
        f32x4 sc[4] = {};
        #pragma unroll
        for (int j = 0; j < 4; ++j) {
            half8 kf0 = *(const half8*)&sK[j * 16 + l16][quad * 8];
            half8 kf1 = *(const half8*)&sK[j * 16 + l16][32 + quad * 8];
            sc[j] = __builtin_amdgcn_mfma_f32_16x16x32_f16(kf0, qf0, sc[j], 0, 0, 0);
            sc[j] = __builtin_amdgcn_mfma_f32_16x16x32_f16(kf1, qf1, sc[j], 0, 0, 0);
        }

        // bias: idx = kpos - q + q0 + 63; lane's 16 indices are bbase + j*16 + r
        const int bbase = kt * 64 + quad * 4 - wave * 16 - l16 + 63;
        if (kt <= qt - 3 || kt >= qt + 3) {
            // uniform tile: all deltas have |delta| >= 129 >= 91 on one side -> one bucket.
            // Reading sBias[bbase] is therefore identical to the per-element path.
            const float cb = (float)sBias[bbase];
            #pragma unroll
            for (int j = 0; j < 4; ++j)
                #pragma unroll
                for (int r = 0; r < 4; ++r)
                    sc[j][r] += cb;
        } else {
            #pragma unroll
            for (int j = 0; j < 4; ++j)
                #pragma unroll
                for (int r = 0; r < 4; ++r)
                    sc[j][r] += (float)sBias[bbase + j * 16 + r];
        }

        // online softmax: each lane owns one q-row's 16 kpos values
        float mx = fmaxf(fmaxf(fmaxf(sc[0][0], sc[0][1]), fmaxf(sc[0][2], sc[0][3])),
                         fmaxf(fmaxf(sc[1][0], sc[1][1]), fmaxf(sc[1][2], sc[1][3])));
        mx = fmaxf(mx, fmaxf(fmaxf(fmaxf(sc[2][0], sc[2][1]), fmaxf(sc[2][2], sc[2][3])),
                             fmaxf(fmaxf(sc[3][0], sc[3][1]), fmaxf(sc[3][2], sc[3][3]))));
        mx = fmaxf(mx, __shfl_xor(mx, 16));
        mx = fmaxf(mx, __shfl_xor(mx, 32));
        float mnew = fmaxf(m_run, mx);
        float alpha = __expf(m_run - mnew);
        m_run = mnew;

        float ps = 0.0f;
        #pragma unroll
        for (int j = 0; j < 4; ++j) {
            half4_t pw;
            #pragma unroll
            for (int r = 0; r < 4; ++r) {
                float p = __expf(sc[j][r] - mnew);
                ps += p;
                pw[r] = (_Float16)p;
            }
            *(half4_t*)&sP[wave][l16][j * 16 + quad * 4] = pw;  // P[q=l16][kpos], b64 write
        }
        l_run = l_run * alpha + ps;
        #pragma unroll
        for (int dt = 0; dt < 4; ++dt) acc[dt] *= alpha;
        __syncthreads();   // sP write -> read ordering (R8-proven structure)

        half8 pf0 = *(const half8*)&sP[wave][l16][quad * 8];        // B[n=q][k=kpos 0..31]
        half8 pf1 = *(const half8*)&sP[wave][l16][32 + quad * 8];   // kpos 32..63
        #pragma unroll
        for (int dt = 0; dt < 4; ++dt) {
            half8 vf0 = *(const half8*)&sVt[dt * 16 + l16][quad * 8];      // A[m=d][k=kpos]
            half8 vf1 = *(const half8*)&sVt[dt * 16 + l16][32 + quad * 8];
            acc[dt] = __builtin_amdgcn_mfma_f32_16x16x32_f16(vf0, pf0, acc[dt], 0, 0, 0);
            acc[dt] = __builtin_amdgcn_mfma_f32_16x16x32_f16(vf1, pf1, acc[dt], 0, 0, 0);
        }
    }

    // final: reduce row-sum across quads, normalize, store half4 chunks
    l_run += __shfl_xor(l_run, 16);
    l_run += __shfl_xor(l_run, 32);
    const float inv = 1.0f / l_run;
    const size_t qg = (size_t)(b * 1024 + q0 + wave * 16 + l16);
    #pragma unroll
    for (int dt = 0; dt < 4; ++dt) {
        half4_t o;
        #pragma unroll
        for (int r = 0; r < 4; ++r) o[r] = (_Float16)(acc[dt][r] * inv);
        *(half4_t*)&ctx[qg * 1024 + h * 64 + dt * 16 + quad * 4] = o;
    }
}

// ---------------- launch ----------------
extern "C" void kernel_launch(void* const* d_in, const int* in_sizes, int n_in,
                              void* d_out, int out_size, void* d_ws, size_t ws_size,
                              hipStream_t stream) {
    const float* hidden   = (const float*)d_in[0];
    const float* Wq       = (const float*)d_in[1];
    const float* Wk       = (const float*)d_in[2];
    const float* Wv       = (const float*)d_in[3];
    const float* Wo       = (const float*)d_in[4];
    const float* rel_bias = (const float*)d_in[5];
    float* out = (float*)d_out;

    _Float16* ws    = (_Float16*)d_ws;
    _Float16* h16   = ws;                     // 4M halves (reused as VT after gemm<0>)
    _Float16* wq16  = ws + 4 * (size_t)MEG;
    _Float16* wk16  = ws + 5 * (size_t)MEG;
    _Float16* wv16  = ws + 6 * (size_t)MEG;
    _Float16* wo16  = ws + 7 * (size_t)MEG;
    _Float16* Qs    = ws + 8 * (size_t)MEG;   // [B,H,S,64]
    _Float16* Ks    = ws + 12 * (size_t)MEG;
    _Float16* Vs    = ws + 16 * (size_t)MEG;
    _Float16* ctx16 = ws + 20 * (size_t)MEG;  // [B*S,1024]
    _Float16* VTs   = h16;                    // V^T [B,H,64,S] — h16 dead after gemm<0>

    cvt_all_kernel<<<8192, 256, 0, stream>>>(hidden, Wq, Wk, Wv, Wo, ws);

    gemm_kernel<0><<<dim3(8, 32, 3), 256, 0, stream>>>(
        h16, wq16, wk16, wv16, Qs, Ks, Vs, nullptr);

    transpose_v_kernel<<<dim3(16, 64), 256, 0, stream>>>(Vs, VTs);

    attn_kernel<<<dim3(16, 16, 4), 256, 0, stream>>>(Qs, Ks, VTs, rel_bias, ctx16);

    gemm_kernel<1><<<dim3(8, 32, 1), 256, 0, stream>>>(
        ctx16, wo16, nullptr, nullptr, nullptr, nullptr, nullptr, out);
}